// Round 11
// baseline (431.582 us; speedup 1.0000x reference)
//
#include <hip/hip_runtime.h>
#include <hip/hip_bf16.h>

// DecoderInputEmbedding — B=4, T=1024, F=6144 (SW=96 x FB=64), EMB=512, H=3, dh=32.
// All inputs fp32 (o_enc int32), output fp32. Internals bf16 (2%-rel threshold).
// R11: FFN1 moved to register-fragment pipeline (barriers 19->3, wb LDS gone);
// gemm pipeline reordered write-first so loads get a full iteration of latency.
//
// ws layout (bytes):
//   M    @ 0          bf16 4096x6144
//   Y    @ 50331648   fp32 4096x512
//   sums @ 58720256   2 floats
//   bids @ 58720320   4x1024 int
//   Wc   @ 58736768   canonical bf16 weights

typedef __attribute__((ext_vector_type(8))) short bf16x8;   // 8 bf16 = 4 VGPR
typedef __attribute__((ext_vector_type(4))) float f32x4;    // MFMA C/D

struct PtrTab { const void* p[16]; };

enum : int {
  O_WQT = 0,        // [96][104]  W^T padded
  O_BQ  = 9984,
  O_WKT = 10080,
  O_BK  = 20064,
  O_WVT = 20160,
  O_BV  = 30144,
  O_ER  = 30240,    // [64][32]
  O_W1T = 32288,    // [384][104]
  O_B1  = 72224,
  O_W2C = 72608,    // [12][96][40]  W2^T k-chunks of 32, padded to 40
  O_B2  = 118688,
  O_WET = 118784    // [8 nt][96 kt][64 n'][64 k']
};

__device__ __forceinline__ float b2f(__hip_bfloat16 v) { return __bfloat162float(v); }
__device__ __forceinline__ __hip_bfloat16 f2b(float v) { return __float2bfloat16(v); }

// prep: We transpose (per-block tile) + weight convert (grid-stride) + zero sums
__global__ __launch_bounds__(256) void prep_kernel(PtrTab tab,
                                                   __hip_bfloat16* __restrict__ Wc,
                                                   float* __restrict__ sums)
{
    __shared__ __hip_bfloat16 tile[64][65];
    const int bid = blockIdx.x, tid = threadIdx.x;
    const int kt = bid % 96, nt = bid / 96;
    const float* We = (const float*)tab.p[14];
    const int k0 = kt * 64, n0 = nt * 64;
    for (int e = tid; e < 4096; e += 256) {
        int kk = e >> 6, nn = e & 63;
        tile[nn][kk] = f2b(We[(size_t)(k0 + kk) * 512 + n0 + nn]);
    }
    __syncthreads();
    __hip_bfloat16* dstT = Wc + O_WET + ((size_t)nt * 96 + kt) * 4096;
    for (int e = tid; e < 4096; e += 256) dstT[e] = tile[e >> 6][e & 63];

    const int g = bid * 256 + tid;
    const int stride = gridDim.x * 256;
    const float* Wq = (const float*)tab.p[3];
    const float* bq = (const float*)tab.p[4];
    const float* Wk = (const float*)tab.p[5];
    const float* bk = (const float*)tab.p[6];
    const float* Wv = (const float*)tab.p[7];
    const float* bv = (const float*)tab.p[8];
    const float* Er = (const float*)tab.p[9];
    const float* W1 = (const float*)tab.p[10];
    const float* b1 = (const float*)tab.p[11];
    const float* W2 = (const float*)tab.p[12];
    const float* b2 = (const float*)tab.p[13];

    for (int t = 0; t < 3; ++t) {
        const float* W = (t == 0 ? Wq : t == 1 ? Wk : Wv);
        __hip_bfloat16* d = Wc + t * 10080;
        for (int i = g; i < 9984; i += stride) {
            int j = i / 104, c = i - j * 104;
            d[i] = (c < 96) ? f2b(W[c * 96 + j]) : f2b(0.0f);
        }
    }
    for (int i = g; i < 96; i += stride) {
        Wc[O_BQ + i] = f2b(bq[i]);
        Wc[O_BK + i] = f2b(bk[i]);
        Wc[O_BV + i] = f2b(bv[i]);
        Wc[O_B2 + i] = f2b(b2[i]);
    }
    for (int i = g; i < 2048; i += stride) Wc[O_ER + i] = f2b(Er[i]);
    for (int i = g; i < 39936; i += stride) {
        int j = i / 104, c = i - j * 104;
        Wc[O_W1T + i] = (c < 96) ? f2b(W1[c * 384 + j]) : f2b(0.0f);
    }
    for (int i = g; i < 384; i += stride) Wc[O_B1 + i] = f2b(b1[i]);
    for (int i = g; i < 46080; i += stride) {
        int kc = i / 3840, r = i - kc * 3840;
        int nn = r / 40, kk = r - nn * 40;
        Wc[O_W2C + i] = (kk < 32) ? f2b(W2[(kc * 32 + kk) * 96 + nn]) : f2b(0.0f);
    }
    if (g < 2) sums[g] = 0.f;
}

// Fragment layouts (HW-verified): A: m=lane&15, k=quad*8+j; B from B^T same;
// C/D: col=lane&15, row=quad*4+reg.
__global__ __launch_bounds__(256) void attn_ffn_kernel(
    const float* __restrict__ x, const __hip_bfloat16* __restrict__ Wc,
    __hip_bfloat16* __restrict__ M)
{
    const int n = blockIdx.x, tid = threadIdx.x;
    const int w = tid >> 6, lane = tid & 63, quad = lane >> 4, ln = lane & 15;

    // LDS layout (49,664 B -> 3 blocks/CU); wb removed (FFN1 now in registers)
    __shared__ __align__(16) char smem[49664];
    __hip_bfloat16* xs  = (__hip_bfloat16*)(smem);          // [64][104] x / att
    __hip_bfloat16* PB  = (__hip_bfloat16*)(smem + 13312);  // [64][72] qer / P
    __hip_bfloat16* kS  = (__hip_bfloat16*)(smem + 22528);  // [64][104] Qscr / K
    __hip_bfloat16* vT  = (__hip_bfloat16*)(smem + 35840);  // [96][72] V^T
    __hip_bfloat16* hid = (__hip_bfloat16*)(smem + 22528);  // [64][200] (phase C)

    const f32x4 z4 = {0.f, 0.f, 0.f, 0.f};
    const int rowb = 16 * w + quad * 4;

    // preload first A-stage weight fragments (Wq rows 0..47)
    bf16x8 wf[9], wfn[9];
    #pragma unroll
    for (int i = 0; i < 9; ++i)
        wf[i] = *(const bf16x8*)(Wc + O_WQT + ((i % 3) * 16 + ln) * 104 + (i / 3) * 32 + quad * 8);

    // stage x: lane-per-row (f=lane), b128 LDS writes
    {
        const float* xb = x + (size_t)n * 6144;
        const int sb = w * 24;
        for (int c = 0; c < 3; ++c) {
            float v[8];
            #pragma unroll
            for (int j = 0; j < 8; ++j) v[j] = xb[(sb + c * 8 + j) * 64 + lane];
            union { __hip_bfloat16 h[8]; bf16x8 v8; } pk;
            #pragma unroll
            for (int j = 0; j < 8; ++j) pk.h[j] = f2b(v[j]);
            *(bf16x8*)(xs + lane * 104 + sb + c * 8) = pk.v8;
        }
    }
    __syncthreads();                                        // barrier 1

    bf16x8 aqr[3];                                          // Q A-frags (regs)

    // ---------- phase A: Q/K/V via register weight frags (no barriers) ----------
    for (int st = 0; st < 6; ++st) {
        const int t = st >> 1, half = st & 1;
        if (st < 5) {
            const __hip_bfloat16* nb = Wc + ((st + 1) >> 1) * 10080 + ((st + 1) & 1) * 4992;
            #pragma unroll
            for (int i = 0; i < 9; ++i)
                wfn[i] = *(const bf16x8*)(nb + ((i % 3) * 16 + ln) * 104 + (i / 3) * 32 + quad * 8);
        }
        f32x4 acc[3] = {z4, z4, z4};
        #pragma unroll
        for (int ks = 0; ks < 3; ++ks) {
            bf16x8 a = *(const bf16x8*)(xs + (16 * w + ln) * 104 + ks * 32 + quad * 8);
            #pragma unroll
            for (int ct = 0; ct < 3; ++ct)
                acc[ct] = __builtin_amdgcn_mfma_f32_16x16x32_bf16(a, wf[ks * 3 + ct], acc[ct], 0, 0, 0);
        }
        const int j0 = half * 48;
        const __hip_bfloat16* bt = Wc + 9984 + t * 10080;
        #pragma unroll
        for (int ct = 0; ct < 3; ++ct) {
            int col = j0 + ct * 16 + ln;
            float bb = b2f(bt[col]);
            if (t < 2) {
                #pragma unroll
                for (int r = 0; r < 4; ++r)
                    kS[(rowb + r) * 104 + col] = f2b(acc[ct][r] + bb);
            } else {                                        // V^T packed uint2
                union { __hip_bfloat16 h4[4]; uint2 u; } pk;
                #pragma unroll
                for (int r = 0; r < 4; ++r) pk.h4[r] = f2b(acc[ct][r] + bb);
                *(uint2*)(vT + col * 72 + rowb) = pk.u;
            }
        }
        if (t == 0 && half == 1) {                          // own-wave rows
            #pragma unroll
            for (int h = 0; h < 3; ++h)
                aqr[h] = *(const bf16x8*)(kS + (16 * w + ln) * 104 + h * 32 + quad * 8);
        }
        #pragma unroll
        for (int i = 0; i < 9; ++i) wf[i] = wfn[i];
    }

    bf16x8 erf[4];
    #pragma unroll
    for (int tn = 0; tn < 4; ++tn)
        erf[tn] = *(const bf16x8*)(Wc + O_ER + (16 * tn + ln) * 32 + quad * 8);
    __syncthreads();                                        // barrier 2: K/V visible

    // FFN1 stage-0 fragments prefetch (consumed in phase C)
    bf16x8 w1f[9], w1fn[9];
    #pragma unroll
    for (int i = 0; i < 9; ++i)
        w1f[i] = *(const bf16x8*)(Wc + O_W1T + ((i % 3) * 16 + ln) * 104 + (i / 3) * 32 + quad * 8);

    // ---------- phase B: MFMA attention (barrier-free) ----------
    for (int h = 0; h < 3; ++h) {
        const int c0 = h * 32;
        bf16x8 aq = aqr[h];
        #pragma unroll
        for (int tn = 0; tn < 4; ++tn) {                    // Qer -> PB (own rows)
            f32x4 q4 = __builtin_amdgcn_mfma_f32_16x16x32_bf16(aq, erf[tn], z4, 0, 0, 0);
            #pragma unroll
            for (int r = 0; r < 4; ++r)
                PB[(rowb + r) * 72 + 16 * tn + ln] = f2b(q4[r]);
        }
        float sco[4][4];
        #pragma unroll
        for (int tn = 0; tn < 4; ++tn) {
            bf16x8 kf = *(const bf16x8*)(kS + (16 * tn + ln) * 104 + c0 + quad * 8);
            f32x4 s1 = __builtin_amdgcn_mfma_f32_16x16x32_bf16(aq, kf, z4, 0, 0, 0);
            #pragma unroll
            for (int r = 0; r < 4; ++r) sco[tn][r] = s1[r];
        }
        #pragma unroll
        for (int tn = 0; tn < 4; ++tn)
            #pragma unroll
            for (int r = 0; r < 4; ++r) {
                int row = rowb + r, col = 16 * tn + ln;
                if (col <= row)
                    sco[tn][r] = (sco[tn][r] + b2f(PB[row * 72 + col + 63 - row]))
                                 * 0.17677669529663687f;
                else
                    sco[tn][r] = -3.0e38f;
            }
        float mx[4], sm[4];
        #pragma unroll
        for (int r = 0; r < 4; ++r) {
            float m0 = fmaxf(fmaxf(sco[0][r], sco[1][r]), fmaxf(sco[2][r], sco[3][r]));
            #pragma unroll
            for (int d = 1; d < 16; d <<= 1) m0 = fmaxf(m0, __shfl_xor(m0, d, 64));
            mx[r] = m0;
        }
        #pragma unroll
        for (int tn = 0; tn < 4; ++tn)
            #pragma unroll
            for (int r = 0; r < 4; ++r) sco[tn][r] = __expf(sco[tn][r] - mx[r]);
        #pragma unroll
        for (int r = 0; r < 4; ++r) {
            float s0 = sco[0][r] + sco[1][r] + sco[2][r] + sco[3][r];
            #pragma unroll
            for (int d = 1; d < 16; d <<= 1) s0 += __shfl_xor(s0, d, 64);
            sm[r] = 1.0f / s0;
        }
        #pragma unroll
        for (int tn = 0; tn < 4; ++tn)
            #pragma unroll
            for (int r = 0; r < 4; ++r)
                PB[(rowb + r) * 72 + 16 * tn + ln] = f2b(sco[tn][r] * sm[r]);
        f32x4 oacc[2] = {z4, z4};
        #pragma unroll
        for (int ks2 = 0; ks2 < 2; ++ks2) {
            bf16x8 pa = *(const bf16x8*)(PB + (16 * w + ln) * 72 + ks2 * 32 + quad * 8);
            #pragma unroll
            for (int t2 = 0; t2 < 2; ++t2) {
                bf16x8 vb = *(const bf16x8*)(vT + (c0 + 16 * t2 + ln) * 72 + ks2 * 32 + quad * 8);
                oacc[t2] = __builtin_amdgcn_mfma_f32_16x16x32_bf16(pa, vb, oacc[t2], 0, 0, 0);
            }
        }
        #pragma unroll
        for (int t2 = 0; t2 < 2; ++t2)
            #pragma unroll
            for (int r = 0; r < 4; ++r)
                xs[(rowb + r) * 104 + c0 + 16 * t2 + ln] = f2b(oacc[t2][r]);
    }
    __syncthreads();                                        // barrier 3: hid overlays kS/vT

    // ---------- phase C: FFN, all register weight frags (no barriers) ----------
    f32x4 acc2[6] = {z4, z4, z4, z4, z4, z4};
    bf16x8 w2f[6], w2fn[6];
    for (int jh = 0; jh < 2; ++jh) {
        for (int cc = 0; cc < 4; ++cc) {                    // FFN1 stages
            const int s = jh * 4 + cc;
            const int j0g = s * 48;
            if (cc < 3) {                                   // prefetch next W1 stage
                const __hip_bfloat16* nb = Wc + O_W1T + (s + 1) * 4992;
                #pragma unroll
                for (int i = 0; i < 9; ++i)
                    w1fn[i] = *(const bf16x8*)(nb + ((i % 3) * 16 + ln) * 104 + (i / 3) * 32 + quad * 8);
            } else {                                        // prefetch FFN2 chunk 0
                const __hip_bfloat16* nb = Wc + O_W2C + (jh * 6) * 3840;
                #pragma unroll
                for (int ct = 0; ct < 6; ++ct)
                    w2f[ct] = *(const bf16x8*)(nb + (ct * 16 + ln) * 40 + quad * 8);
            }
            f32x4 a1[3] = {z4, z4, z4};
            #pragma unroll
            for (int ks = 0; ks < 3; ++ks) {
                bf16x8 a = *(const bf16x8*)(xs + (16 * w + ln) * 104 + ks * 32 + quad * 8);
                #pragma unroll
                for (int ct = 0; ct < 3; ++ct)
                    a1[ct] = __builtin_amdgcn_mfma_f32_16x16x32_bf16(a, w1f[ks * 3 + ct], a1[ct], 0, 0, 0);
            }
            #pragma unroll
            for (int ct = 0; ct < 3; ++ct) {
                int colg = j0g + ct * 16 + ln;
                int coll = cc * 48 + ct * 16 + ln;
                float bb = b2f(Wc[O_B1 + colg]);
                #pragma unroll
                for (int r = 0; r < 4; ++r)
                    hid[(rowb + r) * 200 + coll] = f2b(fmaxf(a1[ct][r] + bb, 0.f));
            }
            if (cc < 3) {
                #pragma unroll
                for (int i = 0; i < 9; ++i) w1f[i] = w1fn[i];
            }
        }
        for (int kc = 0; kc < 6; ++kc) {                    // FFN2 (reg frags)
            if (kc < 5) {
                const __hip_bfloat16* nb = Wc + O_W2C + (jh * 6 + kc + 1) * 3840;
                #pragma unroll
                for (int ct = 0; ct < 6; ++ct)
                    w2fn[ct] = *(const bf16x8*)(nb + (ct * 16 + ln) * 40 + quad * 8);
            } else if (jh == 0) {                           // prefetch FFN1 jh1 stage
                const __hip_bfloat16* nb = Wc + O_W1T + 4 * 4992;
                #pragma unroll
                for (int i = 0; i < 9; ++i)
                    w1f[i] = *(const bf16x8*)(nb + ((i % 3) * 16 + ln) * 104 + (i / 3) * 32 + quad * 8);
            }
            bf16x8 a = *(const bf16x8*)(hid + (16 * w + ln) * 200 + kc * 32 + quad * 8);
            #pragma unroll
            for (int ct = 0; ct < 6; ++ct)
                acc2[ct] = __builtin_amdgcn_mfma_f32_16x16x32_bf16(a, w2f[ct], acc2[ct], 0, 0, 0);
            if (kc < 5) {
                #pragma unroll
                for (int ct = 0; ct < 6; ++ct) w2f[ct] = w2fn[ct];
            }
        }
    }

    // epilogue: M[n][d*64 + l] = acc2 + b2[d], packed 8B stores
    __hip_bfloat16* Mg = M + (size_t)n * 6144;
    #pragma unroll
    for (int ct = 0; ct < 6; ++ct) {
        int d = ct * 16 + ln;
        float bb = b2f(Wc[O_B2 + d]);
        union { __hip_bfloat16 h4[4]; uint2 u; } pk;
        #pragma unroll
        for (int r = 0; r < 4; ++r) pk.h4[r] = f2b(acc2[ct][r] + bb);
        *(uint2*)((char*)Mg + (size_t)(d * 64 + rowb) * 2) = pk.u;
    }
}

// Y = A @ We + be (+ fused mean/var partials). Double-buffered LDS, write-first
// pipeline: iter kt writes tile kt+1 (loaded last iter), issues loads for kt+2,
// then MFMAs tile kt -> loads get a full iteration of latency.
__global__ __launch_bounds__(256) void gemm_kernel(
    const __hip_bfloat16* __restrict__ A,    // 4096 x 6144 (M workspace)
    const __hip_bfloat16* __restrict__ Wc,
    const float* __restrict__ be,            // fp32 bias (512)
    float* __restrict__ Y,                   // 4096 x 512
    float* __restrict__ sums)                // 2 floats (pre-zeroed)
{
    __shared__ __align__(16) __hip_bfloat16 As[2][64 * 72];
    __shared__ __align__(16) __hip_bfloat16 Bs[2][64 * 72];
    const int row0 = blockIdx.x * 64, nt = blockIdx.y, col0 = nt * 64;
    const int tid = threadIdx.x;
    const int w = tid >> 6, lane = tid & 63, quad = lane >> 4, ln = lane & 15;
    const int r0 = tid >> 3, c0_ = (tid & 7) * 8;
    const int r1 = r0 + 32,  c1_ = c0_;
    const size_t abase0 = (size_t)(row0 + r0) * 6144 + c0_;
    const size_t abase1 = (size_t)(row0 + r1) * 6144 + c1_;
    const __hip_bfloat16* Bsrc = Wc + O_WET + (size_t)nt * 96 * 4096;
    const size_t bbase0 = (size_t)r0 * 64 + c0_;
    const size_t bbase1 = (size_t)r1 * 64 + c1_;

    const f32x4 z4 = {0.f, 0.f, 0.f, 0.f};
    f32x4 acc[4] = {z4, z4, z4, z4};

    // tile 0 -> LDS buf0; tile 1 -> regs
    bf16x8 pa0 = *(const bf16x8*)(A + abase0);
    bf16x8 pa1 = *(const bf16x8*)(A + abase1);
    bf16x8 pb0 = *(const bf16x8*)(Bsrc + bbase0);
    bf16x8 pb1 = *(const bf16x8*)(Bsrc + bbase1);
    *(bf16x8*)(&As[0][r0 * 72 + c0_]) = pa0;
    *(bf16x8*)(&As[0][r1 * 72 + c1_]) = pa1;
    *(bf16x8*)(&Bs[0][r0 * 72 + c0_]) = pb0;
    *(bf16x8*)(&Bs[0][r1 * 72 + c1_]) = pb1;
    pa0 = *(const bf16x8*)(A + abase0 + 64);
    pa1 = *(const bf16x8*)(A + abase1 + 64);
    pb0 = *(const bf16x8*)(Bsrc + 4096 + bbase0);
    pb1 = *(const bf16x8*)(Bsrc + 4096 + bbase1);
    __syncthreads();

    for (int kt = 0; kt < 96; ++kt) {
        const int cur = kt & 1;
        if (kt < 95) {                                      // write tile kt+1 (regs)
            *(bf16x8*)(&As[cur ^ 1][r0 * 72 + c0_]) = pa0;
            *(bf16x8*)(&As[cur ^ 1][r1 * 72 + c1_]) = pa1;
            *(bf16x8*)(&Bs[cur ^ 1][r0 * 72 + c0_]) = pb0;
            *(bf16x8*)(&Bs[cur ^ 1][r1 * 72 + c1_]) = pb1;
        }
        if (kt < 94) {                                      // issue loads for kt+2
            pa0 = *(const bf16x8*)(A + abase0 + (kt + 2) * 64);
            pa1 = *(const bf16x8*)(A + abase1 + (kt + 2) * 64);
            pb0 = *(const bf16x8*)(Bsrc + (size_t)(kt + 2) * 4096 + bbase0);
            pb1 = *(const bf16x8*)(Bsrc + (size_t)(kt + 2) * 4096 + bbase1);
        }
        #pragma unroll
        for (int ks = 0; ks < 2; ++ks) {
            bf16x8 a = *(const bf16x8*)(&As[cur][(16 * w + ln) * 72 + ks * 32 + quad * 8]);
            #pragma unroll
            for (int tn = 0; tn < 4; ++tn) {
                bf16x8 b = *(const bf16x8*)(&Bs[cur][(16 * tn + ln) * 72 + ks * 32 + quad * 8]);
                acc[tn] = __builtin_amdgcn_mfma_f32_16x16x32_bf16(a, b, acc[tn], 0, 0, 0);
            }
        }
        __syncthreads();
    }
    float s = 0.f, s2 = 0.f;
    #pragma unroll
    for (int tn = 0; tn < 4; ++tn) {
        int col = col0 + 16 * tn + ln;
        float bb = be[col];
        #pragma unroll
        for (int r = 0; r < 4; ++r) {
            float v = acc[tn][r] + bb;
            Y[(size_t)(row0 + 16 * w + quad * 4 + r) * 512 + col] = v;
            s += v; s2 += v * v;
        }
    }
    #pragma unroll
    for (int off = 1; off < 64; off <<= 1) {
        s  += __shfl_xor(s, off, 64);
        s2 += __shfl_xor(s2, off, 64);
    }
    __shared__ float r1s[4], r2s[4];
    if (lane == 0) { r1s[w] = s; r2s[w] = s2; }
    __syncthreads();
    if (tid == 0) {
        atomicAdd(&sums[0], r1s[0] + r1s[1] + r1s[2] + r1s[3]);
        atomicAdd(&sums[1], r2s[0] + r2s[1] + r2s[2] + r2s[3]);
    }
}

// parallel per-row scan: bid[t] = (incl prefix of o)[t] - o[0]
__global__ __launch_bounds__(256) void segid_kernel(const int* __restrict__ o_enc,
                                                    int* __restrict__ bids) {
    __shared__ int ts[256];
    const int b = blockIdx.x, tid = threadIdx.x;
    const int* o = o_enc + b * 1024;
    int v0 = o[4 * tid], v1 = o[4 * tid + 1], v2 = o[4 * tid + 2], v3 = o[4 * tid + 3];
    int p0 = v0, p1 = p0 + v1, p2 = p1 + v2, p3 = p2 + v3;
    ts[tid] = p3;
    __syncthreads();
    for (int off = 1; off < 256; off <<= 1) {
        int mine = ts[tid];
        int add = (tid >= off) ? ts[tid - off] : 0;
        __syncthreads();
        ts[tid] = mine + add;
        __syncthreads();
    }
    const int excl = (tid > 0) ? ts[tid - 1] : 0;
    const int off0 = o[0];
    int* bid = bids + b * 1024;
    bid[4 * tid]     = excl + p0 - off0;
    bid[4 * tid + 1] = excl + p1 - off0;
    bid[4 * tid + 2] = excl + p2 - off0;
    bid[4 * tid + 3] = excl + p3 - off0;
}

__global__ __launch_bounds__(256) void final_kernel(
    const float* __restrict__ Y, const int* __restrict__ bids,
    const float* __restrict__ sums, const float* __restrict__ r_enc,
    float* __restrict__ out)
{
    const int bt = blockIdx.x;
    const int b = bt >> 10, t = bt & 1023;
    const float mu = sums[0] * (1.0f / 2097152.0f);
    const float var = sums[1] * (1.0f / 2097152.0f) - mu * mu;
    const float rstd = rsqrtf(var + 1e-8f);
    const int* bid = bids + b * 1024;
    const int my = bid[t];
    const bool is_start = (t == 0) || (bid[t - 1] != my);
    int t2 = t + 1;
    float invc = 0.f;
    if (is_start) {
        while (t2 < 1024 && bid[t2] == my) ++t2;
        invc = 1.0f / (float)(t2 - t);
    }
    for (int e = threadIdx.x; e < 512; e += 256) {
        const size_t base = (size_t)bt * 512 + e;
        float res = (Y[base] - mu) * rstd + r_enc[base];
        if (is_start) {
            float s = 0.f;
            for (int tt = t; tt < t2; ++tt)
                s += (Y[((size_t)(b * 1024 + tt)) * 512 + e] - mu) * rstd;
            res += s * invc;
        }
        out[base] = res;
    }
}

extern "C" void kernel_launch(void* const* d_in, const int* in_sizes, int n_in,
                              void* d_out, int out_size, void* d_ws, size_t ws_size,
                              hipStream_t stream) {
    PtrTab tab;
    for (int i = 0; i < 16; ++i) tab.p[i] = d_in[i];

    char* ws = (char*)d_ws;
    __hip_bfloat16* M  = (__hip_bfloat16*)ws;
    float* Y           = (float*)(ws + 50331648);
    float* sums        = (float*)(ws + 58720256);
    int*   bids        = (int*)(ws + 58720320);
    __hip_bfloat16* Wc = (__hip_bfloat16*)(ws + 58736768);

    prep_kernel<<<768, 256, 0, stream>>>(tab, Wc, sums);
    attn_ffn_kernel<<<4096, 256, 0, stream>>>((const float*)d_in[0], Wc, M);
    gemm_kernel<<<dim3(64, 8), 256, 0, stream>>>(M, Wc, (const float*)d_in[15], Y, sums);
    segid_kernel<<<4, 256, 0, stream>>>((const int*)d_in[1], bids);
    final_kernel<<<4096, 256, 0, stream>>>(Y, bids, sums, (const float*)d_in[2], (float*)d_out);
}